// Round 1
// baseline (641.059 us; speedup 1.0000x reference)
//
#include <hip/hip_runtime.h>

// AgriMatcher: normalize -> cosine-sim GEMM -> log-Sinkhorn(5) with dustbin ->
// per-row top-8 + entropy -> 7x7 local variance geometric score -> softmax warp.
// B=2, N=4096=64x64, C=128, K=8, TEMP=0.05, RADIUS=3.

#define NB 2
#define NN 4096
#define NC 128
#define NK 8

constexpr float INV_TEMP   = 20.0f;                  // 1/0.05
constexpr float NORM_CONST = -9.010913347279289f;    // -log(8192)
constexpr float LOG_DUST   = -0.6931471805599453f;   // log(4096)-log(8192)

// ---------------- online logsumexp helpers ----------------
__device__ __forceinline__ void lse_update(float& mx, float& sm, float val) {
  float d = val - mx;
  float e = __expf(-fabsf(d));
  sm = (d > 0.0f) ? fmaf(sm, e, 1.0f) : (sm + e);
  mx = fmaxf(mx, val);
}
__device__ __forceinline__ void lse_merge(float& mx, float& sm, float omx, float osm) {
  float nm = fmaxf(mx, omx);
  sm = sm * __expf(mx - nm) + osm * __expf(omx - nm);
  mx = nm;
}
// 256-thread block LSE reduce (wave shuffle + 4-wave LDS merge). Valid in all threads.
__device__ __forceinline__ float block_lse(float mx, float sm) {
  #pragma unroll
  for (int o = 1; o < 64; o <<= 1) {
    float omx = __shfl_xor(mx, o);
    float osm = __shfl_xor(sm, o);
    lse_merge(mx, sm, omx, osm);
  }
  __shared__ float s_mx[4], s_sm[4];
  int t = threadIdx.x;
  if ((t & 63) == 0) { s_mx[t >> 6] = mx; s_sm[t >> 6] = sm; }
  __syncthreads();
  float fmx = s_mx[0], fsm = s_sm[0];
  #pragma unroll
  for (int i = 1; i < 4; i++) lse_merge(fmx, fsm, s_mx[i], s_sm[i]);
  return fmx + __logf(fsm);
}

// ---------------- 1. L2 normalize rows ----------------
// grid.x = 2*NB*NN (A rows then B rows), 64 threads (1 wave) per row of C=128.
__global__ void norm_kernel(const float* __restrict__ fa, const float* __restrict__ fb,
                            float* __restrict__ na, float* __restrict__ nb) {
  int row = blockIdx.x;
  const float* src;
  float* dst;
  if (row < NB * NN) { src = fa + (size_t)row * NC; dst = na + (size_t)row * NC; }
  else { src = fb + (size_t)(row - NB * NN) * NC; dst = nb + (size_t)(row - NB * NN) * NC; }
  int t = threadIdx.x;
  float x0 = src[t], x1 = src[t + 64];
  float ss = x0 * x0 + x1 * x1;
  #pragma unroll
  for (int o = 32; o; o >>= 1) ss += __shfl_xor(ss, o);
  float nrm = fmaxf(sqrtf(ss), 1e-12f);
  dst[t] = x0 / nrm;
  dst[t + 64] = x1 / nrm;
}

// ---------------- 2. fp32 GEMM: sim = normA . normB^T ----------------
// 64x64 tile / workgroup, 4x4 per thread. A row-major in LDS (stride 68, 2-way
// bank alias only = free), B k-major in LDS so B-frag reads are contiguous cols.
__launch_bounds__(256, 2)
__global__ void gemm_kernel(const float* __restrict__ na, const float* __restrict__ nb,
                            float* __restrict__ sim) {
  __shared__ float As[64 * 68];
  __shared__ float Bs[64 * 68];
  const int b  = blockIdx.z;
  const int m0 = blockIdx.y * 64;
  const int n0 = blockIdx.x * 64;
  const int t  = threadIdx.x;
  const int tx = t & 15, ty = t >> 4;
  float acc[4][4] = {};
  const float* Ab = na + ((size_t)b * NN + m0) * NC;
  const float* Bb = nb + ((size_t)b * NN + n0) * NC;
  for (int koff = 0; koff < NC; koff += 64) {
    #pragma unroll
    for (int ii = 0; ii < 4; ii++) {
      int id  = t + 256 * ii;
      int row = id >> 4, k4 = (id & 15) * 4;
      float4 av = *(const float4*)(Ab + (size_t)row * NC + koff + k4);
      *(float4*)&As[row * 68 + k4] = av;
      float4 bv = *(const float4*)(Bb + (size_t)row * NC + koff + k4);
      Bs[(k4 + 0) * 68 + row] = bv.x;
      Bs[(k4 + 1) * 68 + row] = bv.y;
      Bs[(k4 + 2) * 68 + row] = bv.z;
      Bs[(k4 + 3) * 68 + row] = bv.w;
    }
    __syncthreads();
    #pragma unroll
    for (int kq = 0; kq < 16; kq++) {
      float4 a[4], bv[4];
      #pragma unroll
      for (int i = 0; i < 4; i++) a[i] = *(const float4*)&As[(ty * 4 + i) * 68 + kq * 4];
      #pragma unroll
      for (int j = 0; j < 4; j++) bv[j] = *(const float4*)&Bs[(kq * 4 + j) * 68 + tx * 4];
      const float* ap = (const float*)a;
      const float* bp = (const float*)bv;
      #pragma unroll
      for (int i = 0; i < 4; i++) {
        #pragma unroll
        for (int kx = 0; kx < 4; kx++) {
          float av2 = ap[i * 4 + kx];
          acc[i][0] = fmaf(av2, bp[kx * 4 + 0], acc[i][0]);
          acc[i][1] = fmaf(av2, bp[kx * 4 + 1], acc[i][1]);
          acc[i][2] = fmaf(av2, bp[kx * 4 + 2], acc[i][2]);
          acc[i][3] = fmaf(av2, bp[kx * 4 + 3], acc[i][3]);
        }
      }
    }
    __syncthreads();
  }
  float* ob = sim + ((size_t)b * NN + m0) * NN + n0;
  #pragma unroll
  for (int i = 0; i < 4; i++) {
    float4 o = make_float4(acc[i][0], acc[i][1], acc[i][2], acc[i][3]);
    *(float4*)(ob + (size_t)(ty * 4 + i) * NN + tx * 4) = o;
  }
}

// ---------------- 3a. u-pass: row logsumexp ----------------
// grid (NN+1, NB); block 256. m==NN is the dustbin row (Z=0 -> LSE over v).
__launch_bounds__(256)
__global__ void u_pass(const float* __restrict__ sim, const float* __restrict__ v,
                       float* __restrict__ u) {
  int m = blockIdx.x, b = blockIdx.y, t = threadIdx.x;
  const float* vrow = v + b * (NN + 1);
  float mx = -3.0e38f, sm = 0.0f;
  if (m < NN) {
    const float* srow = sim + ((size_t)b * NN + m) * NN;
    float mx1 = -3.0e38f, sm1 = 0.0f;
    #pragma unroll
    for (int i = 0; i < 16; i += 2) {
      int n0 = t + (i << 8), n1 = n0 + 256;
      lse_update(mx, sm, fmaf(srow[n0], INV_TEMP, vrow[n0]));
      lse_update(mx1, sm1, fmaf(srow[n1], INV_TEMP, vrow[n1]));
    }
    lse_merge(mx, sm, mx1, sm1);
    if (t == 0) lse_update(mx, sm, vrow[NN]);  // dustbin column term
  } else {
    for (int n = t; n <= NN; n += 256) lse_update(mx, sm, vrow[n]);
  }
  float lse = block_lse(mx, sm);
  if (t == 0) u[b * (NN + 1) + m] = ((m < NN) ? NORM_CONST : LOG_DUST) - lse;
}

// ---------------- 3b. v-pass: column logsumexp ----------------
// grid (257, NB): blocks 0..255 each own 16 columns (16 cols x 16 row-strips);
// block 256 does the dustbin column (LSE over u).
__launch_bounds__(256)
__global__ void v_pass(const float* __restrict__ sim, const float* __restrict__ u,
                       float* __restrict__ v) {
  int b = blockIdx.y, t = threadIdx.x;
  const float* urow = u + b * (NN + 1);
  if (blockIdx.x == 256) {
    float mx = -3.0e38f, sm = 0.0f;
    for (int n = t; n <= NN; n += 256) lse_update(mx, sm, urow[n]);
    float lse = block_lse(mx, sm);
    if (t == 0) v[b * (NN + 1) + NN] = LOG_DUST - lse;
    return;
  }
  int c = t & 15, r = t >> 4;
  int col = blockIdx.x * 16 + c;
  const float* sp = sim + (size_t)b * NN * NN + col;
  float mx0 = -3.0e38f, sm0 = 0.0f, mx1 = -3.0e38f, sm1 = 0.0f;
  const float* p = sp + (size_t)r * NN;
  int mm = r;
  for (int j = 0; j < 128; j++) {
    float v0 = fmaf(p[0], INV_TEMP, urow[mm]);
    float v1 = fmaf(p[(size_t)16 * NN], INV_TEMP, urow[mm + 16]);
    lse_update(mx0, sm0, v0);
    lse_update(mx1, sm1, v1);
    p += (size_t)32 * NN;
    mm += 32;
  }
  lse_merge(mx0, sm0, mx1, sm1);
  if (r == 0) lse_update(mx0, sm0, urow[NN]);  // dustbin row: Z=0 -> val=u[M]
  __shared__ float smx[256], ssm[256];
  smx[t] = mx0; ssm[t] = sm0;
  __syncthreads();
  if (r == 0) {
    for (int rr = 1; rr < 16; rr++) lse_merge(mx0, sm0, smx[rr * 16 + c], ssm[rr * 16 + c]);
    v[b * (NN + 1) + col] = NORM_CONST - (mx0 + __logf(sm0));
  }
}

// ---------------- 4. per-row finalize: top-8, row-sum, entropy ----------------
__launch_bounds__(256)
__global__ void finalize_rows(const float* __restrict__ sim, const float* __restrict__ u,
                              const float* __restrict__ v, float* __restrict__ tkv,
                              int* __restrict__ tki, float* __restrict__ ent) {
  int m = blockIdx.x, b = blockIdx.y, t = threadIdx.x;
  const float* srow = sim + ((size_t)b * NN + m) * NN;
  const float* vrow = v + b * (NN + 1);
  float um = u[b * (NN + 1) + m];
  float z[16];
  float se = 0.0f;
  #pragma unroll
  for (int i = 0; i < 16; i++) {
    int n = t + (i << 8);
    z[i] = fmaf(srow[n], INV_TEMP, vrow[n] + um);
    se += __expf(z[i]);
  }
  #pragma unroll
  for (int o = 1; o < 64; o <<= 1) se += __shfl_xor(se, o);
  __shared__ float ssum[4];
  if ((t & 63) == 0) ssum[t >> 6] = se;
  __syncthreads();
  float S = ssum[0] + ssum[1] + ssum[2] + ssum[3];

  // top-8 by iterative argmax (ties -> lowest index, matching lax.top_k)
  __shared__ float rv[256];
  __shared__ int ri[256];
  __shared__ float selv[8];
  __shared__ int seli[8];
  unsigned mask = 0;
  for (int round = 0; round < 8; round++) {
    float best = -3.0e38f; int bi = 0;
    #pragma unroll
    for (int i = 0; i < 16; i++) {
      bool ok = (!(mask & (1u << i))) && (z[i] > best);
      best = ok ? z[i] : best;
      bi = ok ? i : bi;
    }
    rv[t] = best; ri[t] = t + (bi << 8);
    __syncthreads();
    for (int s = 128; s; s >>= 1) {
      if (t < s) {
        float v2 = rv[t + s]; int i2 = ri[t + s];
        if (v2 > rv[t] || (v2 == rv[t] && i2 < ri[t])) { rv[t] = v2; ri[t] = i2; }
      }
      __syncthreads();
    }
    int win = ri[0];
    if (t == 0) { selv[round] = rv[0]; seli[round] = win; }
    if ((win & 255) == t) mask |= 1u << (win >> 8);
    __syncthreads();
  }

  // entropy with the reference's +1e-8 regularizers
  float denom = S + 1e-8f;
  float ep = 0.0f;
  #pragma unroll
  for (int i = 0; i < 16; i++) {
    float pp = __expf(z[i]) / denom;
    ep += pp * __logf(pp + 1e-8f);
  }
  #pragma unroll
  for (int o = 1; o < 64; o <<= 1) ep += __shfl_xor(ep, o);
  __syncthreads();
  if ((t & 63) == 0) ssum[t >> 6] = ep;
  __syncthreads();
  if (t < 8) {
    tkv[((size_t)b * NN + m) * NK + t] = __expf(selv[t]);
    tki[((size_t)b * NN + m) * NK + t] = seli[t];
  }
  if (t == 0) ent[b * NN + m] = -(ssum[0] + ssum[1] + ssum[2] + ssum[3]);
}

// ---------------- 5. geometric score: 7x7 local variance ----------------
// grid (NK, NB); one block per (b,k). Separable box sums of s1=dx+dy, s2=dx^2+dy^2.
__launch_bounds__(256)
__global__ void geo_kernel(const int* __restrict__ tki, const float* __restrict__ posA,
                           const float* __restrict__ posB, float* __restrict__ geo) {
  int k = blockIdx.x, b = blockIdx.y, t = threadIdx.x;
  __shared__ float s1[4096], s2[4096];
  const float* pA = posA + (size_t)b * NN * 2;
  const float* pB = posB + (size_t)b * NN * 2;
  const int* idx = tki + (size_t)b * NN * NK + k;
  #pragma unroll
  for (int i = 0; i < 16; i++) {
    int n = t + (i << 8);
    int j = idx[(size_t)n * NK];
    float dx = pB[(size_t)j * 2]     - pA[(size_t)n * 2];
    float dy = pB[(size_t)j * 2 + 1] - pA[(size_t)n * 2 + 1];
    s1[n] = dx + dy;
    s2[n] = dx * dx + dy * dy;
  }
  __syncthreads();
  // horizontal 7-tap into registers, then overwrite LDS
  float h1[16], h2[16];
  #pragma unroll
  for (int i = 0; i < 16; i++) {
    int n = t + (i << 8);
    int h = n >> 6, w = n & 63;
    float a1 = 0.0f, a2 = 0.0f;
    for (int dw = -3; dw <= 3; dw++) {
      int ww = w + dw;
      if (ww >= 0 && ww < 64) { a1 += s1[h * 64 + ww]; a2 += s2[h * 64 + ww]; }
    }
    h1[i] = a1; h2[i] = a2;
  }
  __syncthreads();
  #pragma unroll
  for (int i = 0; i < 16; i++) {
    int n = t + (i << 8);
    s1[n] = h1[i]; s2[n] = h2[i];
  }
  __syncthreads();
  #pragma unroll
  for (int i = 0; i < 16; i++) {
    int n = t + (i << 8);
    int h = n >> 6, w = n & 63;
    float b1 = 0.0f, b2 = 0.0f;
    for (int dh = -3; dh <= 3; dh++) {
      int hh = h + dh;
      if (hh >= 0 && hh < 64) { b1 += s1[hh * 64 + w]; b2 += s2[hh * 64 + w]; }
    }
    // unbiased var over 98 values (2 channels x 49 taps, zeros included)
    float mean = b1 * (1.0f / 98.0f);
    float var = (b2 - b1 * mean) * (1.0f / 97.0f);
    geo[((size_t)b * NN + n) * NK + k] = 1.0f / (1.0f + var * 100.0f);
  }
}

// ---------------- 6. combine: softmax over K, weighted warp ----------------
__launch_bounds__(256)
__global__ void combine_kernel(const float* __restrict__ tkv, const float* __restrict__ geo,
                               const int* __restrict__ tki, const float* __restrict__ posB,
                               float* __restrict__ warp) {
  int id = blockIdx.x * 256 + threadIdx.x;  // b*NN + n
  int b = id / NN;
  const float* vals = tkv + (size_t)id * NK;
  const float* g    = geo + (size_t)id * NK;
  const int*   ix   = tki + (size_t)id * NK;
  const float* pB   = posB + (size_t)b * NN * 2;
  float l[8], mx = -3.0e38f;
  #pragma unroll
  for (int j = 0; j < 8; j++) {
    l[j] = (vals[j] + 1.5f * g[j]) * INV_TEMP;
    mx = fmaxf(mx, l[j]);
  }
  float sw = 0.0f, wx = 0.0f, wy = 0.0f;
  #pragma unroll
  for (int j = 0; j < 8; j++) {
    float w = __expf(l[j] - mx);
    int jj = ix[j];
    sw += w;
    wx = fmaf(w, pB[(size_t)jj * 2], wx);
    wy = fmaf(w, pB[(size_t)jj * 2 + 1], wy);
  }
  warp[(size_t)id * 2]     = wx / sw;
  warp[(size_t)id * 2 + 1] = wy / sw;
}

extern "C" void kernel_launch(void* const* d_in, const int* in_sizes, int n_in,
                              void* d_out, int out_size, void* d_ws, size_t ws_size,
                              hipStream_t stream) {
  const float* fA = (const float*)d_in[0];
  const float* fB = (const float*)d_in[1];
  const float* pA = (const float*)d_in[2];
  const float* pB = (const float*)d_in[3];

  float* out  = (float*)d_out;
  float* warp = out;                       // [B,N,2]
  float* ent  = out + (size_t)NB * NN * 2; // [B,N]
  float* sim  = ent + (size_t)NB * NN;     // [B,N,N] raw_sim (also Sinkhorn cost)

  float* normA = (float*)d_ws;
  float* normB = normA + (size_t)NB * NN * NC;
  float* uu    = normB + (size_t)NB * NN * NC;
  float* vv    = uu + NB * (NN + 1);
  float* tkv   = vv + NB * (NN + 1);
  int*   tki   = (int*)(tkv + (size_t)NB * NN * NK);
  float* geo   = (float*)(tki + (size_t)NB * NN * NK);

  hipMemsetAsync(vv, 0, NB * (NN + 1) * sizeof(float), stream);

  norm_kernel<<<dim3(2 * NB * NN), 64, 0, stream>>>(fA, fB, normA, normB);
  gemm_kernel<<<dim3(NN / 64, NN / 64, NB), 256, 0, stream>>>(normA, normB, sim);
  for (int it = 0; it < 5; it++) {
    u_pass<<<dim3(NN + 1, NB), 256, 0, stream>>>(sim, vv, uu);
    v_pass<<<dim3(257, NB), 256, 0, stream>>>(sim, uu, vv);
  }
  finalize_rows<<<dim3(NN, NB), 256, 0, stream>>>(sim, uu, vv, tkv, tki, ent);
  geo_kernel<<<dim3(NK, NB), 256, 0, stream>>>(tki, pA, pB, geo);
  combine_kernel<<<dim3((NB * NN) / 256), 256, 0, stream>>>(tkv, geo, tki, pB, warp);
}

// Round 2
// 512.469 us; speedup vs baseline: 1.2509x; 1.2509x over previous
//
#include <hip/hip_runtime.h>
#include <hip/hip_bf16.h>

// AgriMatcher: normalize(+bf16 hi/lo split) -> MFMA cosine-sim GEMM ->
// fixed-shift log-Sinkhorn(5) with dustbin -> per-row top-8 + entropy ->
// 7x7 local variance geometric score -> softmax warp.
// B=2, N=4096=64x64, C=128, K=8, TEMP=0.05, RADIUS=3.

#define NB 2
#define NN 4096
#define NC 128
#define NK 8

constexpr float INV_TEMP   = 20.0f;                  // 1/0.05
constexpr float NORM_CONST = -9.010913347279289f;    // -log(8192)
constexpr float LOG_DUST   = -0.6931471805599453f;   // log(4096)-log(8192)
constexpr float SHIFT      = 30.0f;                  // fixed LSE shift: args <= ~25 always
constexpr float EPS_SH     = 9.357623e-22f;          // 1e-8 * exp(-SHIFT)

typedef __attribute__((ext_vector_type(8))) short bf16x8;
typedef __attribute__((ext_vector_type(4))) float f32x4;

// ---------------- 1. L2 normalize rows + bf16 hi/lo split ----------------
// grid.x = 2*NB*NN (A rows then B rows), 64 threads (1 wave) per row of C=128.
__global__ void norm_split(const float* __restrict__ fa, const float* __restrict__ fb,
                           __hip_bfloat16* __restrict__ Ah, __hip_bfloat16* __restrict__ Al,
                           __hip_bfloat16* __restrict__ Bh, __hip_bfloat16* __restrict__ Bl) {
  int row = blockIdx.x;
  bool isB = row >= NB * NN;
  int base = isB ? row - NB * NN : row;
  const float* src = (isB ? fb : fa) + (size_t)base * NC;
  __hip_bfloat16* dh = (isB ? Bh : Ah) + (size_t)base * NC;
  __hip_bfloat16* dl = (isB ? Bl : Al) + (size_t)base * NC;
  int t = threadIdx.x;
  float x0 = src[t], x1 = src[t + 64];
  float ss = x0 * x0 + x1 * x1;
  #pragma unroll
  for (int o = 32; o; o >>= 1) ss += __shfl_xor(ss, o);
  float nrm = fmaxf(sqrtf(ss), 1e-12f);
  float y0 = x0 / nrm, y1 = x1 / nrm;
  __hip_bfloat16 h0 = __float2bfloat16(y0);
  __hip_bfloat16 h1 = __float2bfloat16(y1);
  dh[t] = h0;      dl[t] = __float2bfloat16(y0 - __bfloat162float(h0));
  dh[t + 64] = h1; dl[t + 64] = __float2bfloat16(y1 - __bfloat162float(h1));
}

// ---------------- 2. MFMA GEMM: sim = A . B^T via bf16 hi/lo split ----------------
// 128x128 tile / 256 threads (4 waves 2x2), K=128 in two 64-chunks.
// LDS XOR-swizzled (k-chunk ^ row&7) so both staging stores and b128 frag reads
// are conflict-free without padding. acc += Ah*Bh + Ah*Bl + Al*Bh (Al*Bl ~2^-18, dropped).
__launch_bounds__(256, 2)
__global__ void gemm_mfma(const __hip_bfloat16* __restrict__ Ah, const __hip_bfloat16* __restrict__ Al,
                          const __hip_bfloat16* __restrict__ Bh, const __hip_bfloat16* __restrict__ Bl,
                          float* __restrict__ sim) {
  __shared__ __hip_bfloat16 sAh[128 * 64], sAl[128 * 64];
  __shared__ __hip_bfloat16 sBh[128 * 64], sBl[128 * 64];
  const int b = blockIdx.z, m0 = blockIdx.y * 128, n0 = blockIdx.x * 128;
  const int t = threadIdx.x;
  const int wid = t >> 6, l = t & 63, q = l >> 4, lm = l & 15;
  const int wm = (wid >> 1) * 64, wn = (wid & 1) * 64;
  f32x4 acc[4][4] = {};
  const __hip_bfloat16* gAh = Ah + ((size_t)b * NN + m0) * NC;
  const __hip_bfloat16* gAl = Al + ((size_t)b * NN + m0) * NC;
  const __hip_bfloat16* gBh = Bh + ((size_t)b * NN + n0) * NC;
  const __hip_bfloat16* gBl = Bl + ((size_t)b * NN + n0) * NC;

  for (int koff = 0; koff < NC; koff += 64) {
    #pragma unroll
    for (int ii = 0; ii < 4; ii++) {
      int id = t + 256 * ii;
      int row = id >> 3, cc = id & 7;
      int gofs = row * NC + koff + cc * 8;
      int lofs = row * 64 + ((cc ^ (row & 7)) << 3);
      *(float4*)&sAh[lofs] = *(const float4*)(gAh + gofs);
      *(float4*)&sAl[lofs] = *(const float4*)(gAl + gofs);
      *(float4*)&sBh[lofs] = *(const float4*)(gBh + gofs);
      *(float4*)&sBl[lofs] = *(const float4*)(gBl + gofs);
    }
    __syncthreads();
    #pragma unroll
    for (int ks = 0; ks < 2; ks++) {
      int cc = ks * 4 + q;
      bf16x8 a_h[4], a_l[4], b_h[4], b_l[4];
      #pragma unroll
      for (int i = 0; i < 4; i++) {
        int r = wm + i * 16 + lm;
        int ro = r * 64 + ((cc ^ (r & 7)) << 3);
        a_h[i] = *(const bf16x8*)&sAh[ro];
        a_l[i] = *(const bf16x8*)&sAl[ro];
        int n = wn + i * 16 + lm;
        int no = n * 64 + ((cc ^ (n & 7)) << 3);
        b_h[i] = *(const bf16x8*)&sBh[no];
        b_l[i] = *(const bf16x8*)&sBl[no];
      }
      #pragma unroll
      for (int i = 0; i < 4; i++) {
        #pragma unroll
        for (int j = 0; j < 4; j++) {
          acc[i][j] = __builtin_amdgcn_mfma_f32_16x16x32_bf16(a_h[i], b_h[j], acc[i][j], 0, 0, 0);
          acc[i][j] = __builtin_amdgcn_mfma_f32_16x16x32_bf16(a_h[i], b_l[j], acc[i][j], 0, 0, 0);
          acc[i][j] = __builtin_amdgcn_mfma_f32_16x16x32_bf16(a_l[i], b_h[j], acc[i][j], 0, 0, 0);
        }
      }
    }
    __syncthreads();
  }
  // C/D layout (m89-verified): col = lane&15, row = (lane>>4)*4 + reg
  float* ob = sim + (size_t)b * NN * NN;
  #pragma unroll
  for (int i = 0; i < 4; i++) {
    #pragma unroll
    for (int j = 0; j < 4; j++) {
      int col = n0 + wn + j * 16 + lm;
      #pragma unroll
      for (int reg = 0; reg < 4; reg++) {
        int r = m0 + wm + i * 16 + q * 4 + reg;
        ob[(size_t)r * NN + col] = acc[i][j][reg];
      }
    }
  }
}

// ---------------- 3a. u-pass: row sum-exp with fixed shift ----------------
// grid (NN+1, NB); block 256. m==NN is the dustbin row (Z=0 -> LSE over v).
__launch_bounds__(256)
__global__ void u_pass(const float* __restrict__ sim, const float* __restrict__ v,
                       float* __restrict__ u) {
  int m = blockIdx.x, b = blockIdx.y, t = threadIdx.x;
  const float* vrow = v + b * (NN + 1);
  float acc = 0.0f;
  if (m < NN) {
    const float4* srow = (const float4*)(sim + ((size_t)b * NN + m) * NN);
    const float4* v4 = (const float4*)vrow;
    #pragma unroll
    for (int i = 0; i < 4; i++) {
      int idx = t + (i << 8);
      float4 s = srow[idx];
      float4 vv = v4[idx];
      acc += __expf(fmaf(s.x, INV_TEMP, vv.x - SHIFT));
      acc += __expf(fmaf(s.y, INV_TEMP, vv.y - SHIFT));
      acc += __expf(fmaf(s.z, INV_TEMP, vv.z - SHIFT));
      acc += __expf(fmaf(s.w, INV_TEMP, vv.w - SHIFT));
    }
    if (t == 0) acc += __expf(vrow[NN] - SHIFT);  // dustbin column (Z=0)
  } else {
    for (int n = t; n <= NN; n += 256) acc += __expf(vrow[n] - SHIFT);
  }
  #pragma unroll
  for (int o = 1; o < 64; o <<= 1) acc += __shfl_xor(acc, o);
  __shared__ float sa[4];
  if ((t & 63) == 0) sa[t >> 6] = acc;
  __syncthreads();
  if (t == 0) {
    float total = sa[0] + sa[1] + sa[2] + sa[3];
    u[b * (NN + 1) + m] = ((m < NN) ? NORM_CONST : LOG_DUST) - (SHIFT + __logf(total));
  }
}

// ---------------- 3b. v-pass: column sum-exp with fixed shift ----------------
// grid (129, NB): blocks 0..127 own 32 columns each (coalesced 128B row strips);
// block 128 does the dustbin column (sum over u).
__launch_bounds__(256)
__global__ void v_pass(const float* __restrict__ sim, const float* __restrict__ u,
                       float* __restrict__ v) {
  int b = blockIdx.y, t = threadIdx.x;
  const float* ub = u + b * (NN + 1);
  if (blockIdx.x == 128) {
    float acc = 0.0f;
    for (int n = t; n <= NN; n += 256) acc += __expf(ub[n] - SHIFT);
    #pragma unroll
    for (int o = 1; o < 64; o <<= 1) acc += __shfl_xor(acc, o);
    __shared__ float sa[4];
    if ((t & 63) == 0) sa[t >> 6] = acc;
    __syncthreads();
    if (t == 0)
      v[b * (NN + 1) + NN] = LOG_DUST - (SHIFT + __logf(sa[0] + sa[1] + sa[2] + sa[3]));
    return;
  }
  __shared__ float u_s[NN];
  for (int n = t; n < NN; n += 256) u_s[n] = ub[n] - SHIFT;
  __syncthreads();
  int c = t & 7, r = t >> 3;
  int col0 = blockIdx.x * 32;
  const float4* base = (const float4*)(sim + (size_t)b * NN * NN);
  float ax = 0.0f, ay = 0.0f, az = 0.0f, aw = 0.0f;
  for (int j = 0; j < 128; j++) {
    int row = (j << 5) + r;
    float um = u_s[row];
    float4 s = base[(size_t)row * (NN >> 2) + (col0 >> 2) + c];
    ax += __expf(fmaf(s.x, INV_TEMP, um));
    ay += __expf(fmaf(s.y, INV_TEMP, um));
    az += __expf(fmaf(s.z, INV_TEMP, um));
    aw += __expf(fmaf(s.w, INV_TEMP, um));
  }
  __shared__ float red[256][4];
  red[t][0] = ax; red[t][1] = ay; red[t][2] = az; red[t][3] = aw;
  __syncthreads();
  for (int s = 128; s >= 8; s >>= 1) {
    if (t < s) {
      red[t][0] += red[t + s][0]; red[t][1] += red[t + s][1];
      red[t][2] += red[t + s][2]; red[t][3] += red[t + s][3];
    }
    __syncthreads();
  }
  if (t < 8) {
    float dust = __expf(ub[NN] - SHIFT);  // dustbin row (Z=0 -> u[M])
    #pragma unroll
    for (int i = 0; i < 4; i++)
      v[b * (NN + 1) + col0 + t * 4 + i] =
          NORM_CONST - (SHIFT + __logf(red[t][i] + dust));
  }
}

// ---------------- 4. per-row finalize: top-8, entropy ----------------
// One exp per element; entropy via H = (T1*log(D) - T2)/D with D = T1 + 1e-8*e^-SHIFT
// (drops sum_p p*log1p(1e-8/p) <= 4e-5, far under threshold). Top-8: wave-local
// shuffle argmax (8 rounds) then a single 4-list merge. Ties -> lowest index.
__launch_bounds__(256)
__global__ void finalize_rows(const float* __restrict__ sim, const float* __restrict__ u,
                              const float* __restrict__ v, float* __restrict__ tkv,
                              int* __restrict__ tki, float* __restrict__ ent) {
  int m = blockIdx.x, b = blockIdx.y, t = threadIdx.x;
  const float4* srow = (const float4*)(sim + ((size_t)b * NN + m) * NN);
  const float4* v4 = (const float4*)(v + b * (NN + 1));
  float um = u[b * (NN + 1) + m];
  float z[16];
  float T1 = 0.0f, T2 = 0.0f;
  #pragma unroll
  for (int i = 0; i < 4; i++) {
    int idx = t + (i << 8);
    float4 s = srow[idx];
    float4 vv = v4[idx];
    float zz;
    zz = fmaf(s.x, INV_TEMP, vv.x + um); z[i * 4 + 0] = zz;
    { float zs = zz - SHIFT, e = __expf(zs); T1 += e; T2 = fmaf(e, zs, T2); }
    zz = fmaf(s.y, INV_TEMP, vv.y + um); z[i * 4 + 1] = zz;
    { float zs = zz - SHIFT, e = __expf(zs); T1 += e; T2 = fmaf(e, zs, T2); }
    zz = fmaf(s.z, INV_TEMP, vv.z + um); z[i * 4 + 2] = zz;
    { float zs = zz - SHIFT, e = __expf(zs); T1 += e; T2 = fmaf(e, zs, T2); }
    zz = fmaf(s.w, INV_TEMP, vv.w + um); z[i * 4 + 3] = zz;
    { float zs = zz - SHIFT, e = __expf(zs); T1 += e; T2 = fmaf(e, zs, T2); }
  }
  // entropy partials: wave reduce then LDS
  float w1 = T1, w2 = T2;
  #pragma unroll
  for (int o = 1; o < 64; o <<= 1) { w1 += __shfl_xor(w1, o); w2 += __shfl_xor(w2, o); }

  // wave-local top-8 (element n = 4t + 1024*chunk + c)
  int wid = t >> 6;
  unsigned mask = 0;
  float wv[8]; int wn8[8];
  #pragma unroll
  for (int round = 0; round < 8; round++) {
    float best = -3.0e38f; int bn = 0x7fffffff;
    #pragma unroll
    for (int i = 0; i < 16; i++) {
      if (!((mask >> i) & 1u)) {
        float zz = z[i];
        int n = 4 * t + ((i >> 2) << 10) + (i & 3);
        if (zz > best || (zz == best && n < bn)) { best = zz; bn = n; }
      }
    }
    #pragma unroll
    for (int o = 1; o < 64; o <<= 1) {
      float ov = __shfl_xor(best, o);
      int on = __shfl_xor(bn, o);
      if (ov > best || (ov == best && on < bn)) { best = ov; bn = on; }
    }
    wv[round] = best; wn8[round] = bn;
    if (((bn >> 2) & 255) == t) mask |= 1u << (((bn >> 10) << 2) | (bn & 3));
  }
  __shared__ float lv[4][8]; __shared__ int ln[4][8];
  __shared__ float fv[8];   __shared__ int fn[8];
  __shared__ float sT1[4], sT2[4];
  if ((t & 63) == 0) {
    sT1[wid] = w1; sT2[wid] = w2;
    #pragma unroll
    for (int j = 0; j < 8; j++) { lv[wid][j] = wv[j]; ln[wid][j] = wn8[j]; }
  }
  __syncthreads();
  if (t == 0) {
    int ptr[4] = {0, 0, 0, 0};
    for (int k = 0; k < 8; k++) {
      float bv2 = -3.0e38f; int bn2 = 0x7fffffff, bw = 0;
      #pragma unroll
      for (int w = 0; w < 4; w++) {
        if (ptr[w] < 8) {
          float cv = lv[w][ptr[w]]; int cn = ln[w][ptr[w]];
          if (cv > bv2 || (cv == bv2 && cn < bn2)) { bv2 = cv; bn2 = cn; bw = w; }
        }
      }
      fv[k] = bv2; fn[k] = bn2; ptr[bw]++;
    }
  }
  __syncthreads();
  size_t ro = ((size_t)b * NN + m) * NK;
  if (t < 8) { tkv[ro + t] = __expf(fv[t]); tki[ro + t] = fn[t]; }
  if (t == 0) {
    float T1t = sT1[0] + sT1[1] + sT1[2] + sT1[3];
    float T2t = sT2[0] + sT2[1] + sT2[2] + sT2[3];
    float denom = T1t + EPS_SH;
    float ld = __logf(denom);
    ent[b * NN + m] = (T1t * ld - T2t) / denom;
  }
}

// ---------------- 5. geometric score: 7x7 local variance ----------------
// grid (NK, NB); one block per (b,k). Separable box sums of s1=dx+dy, s2=dx^2+dy^2.
__launch_bounds__(256)
__global__ void geo_kernel(const int* __restrict__ tki, const float* __restrict__ posA,
                           const float* __restrict__ posB, float* __restrict__ geo) {
  int k = blockIdx.x, b = blockIdx.y, t = threadIdx.x;
  __shared__ float s1[4096], s2[4096];
  const float* pA = posA + (size_t)b * NN * 2;
  const float* pB = posB + (size_t)b * NN * 2;
  const int* idx = tki + (size_t)b * NN * NK + k;
  #pragma unroll
  for (int i = 0; i < 16; i++) {
    int n = t + (i << 8);
    int j = idx[(size_t)n * NK];
    float dx = pB[(size_t)j * 2]     - pA[(size_t)n * 2];
    float dy = pB[(size_t)j * 2 + 1] - pA[(size_t)n * 2 + 1];
    s1[n] = dx + dy;
    s2[n] = dx * dx + dy * dy;
  }
  __syncthreads();
  float h1[16], h2[16];
  #pragma unroll
  for (int i = 0; i < 16; i++) {
    int n = t + (i << 8);
    int h = n >> 6, w = n & 63;
    float a1 = 0.0f, a2 = 0.0f;
    for (int dw = -3; dw <= 3; dw++) {
      int ww = w + dw;
      if (ww >= 0 && ww < 64) { a1 += s1[h * 64 + ww]; a2 += s2[h * 64 + ww]; }
    }
    h1[i] = a1; h2[i] = a2;
  }
  __syncthreads();
  #pragma unroll
  for (int i = 0; i < 16; i++) {
    int n = t + (i << 8);
    s1[n] = h1[i]; s2[n] = h2[i];
  }
  __syncthreads();
  #pragma unroll
  for (int i = 0; i < 16; i++) {
    int n = t + (i << 8);
    int h = n >> 6, w = n & 63;
    float b1 = 0.0f, b2 = 0.0f;
    for (int dh = -3; dh <= 3; dh++) {
      int hh = h + dh;
      if (hh >= 0 && hh < 64) { b1 += s1[hh * 64 + w]; b2 += s2[hh * 64 + w]; }
    }
    float mean = b1 * (1.0f / 98.0f);
    float var = (b2 - b1 * mean) * (1.0f / 97.0f);
    geo[((size_t)b * NN + n) * NK + k] = 1.0f / (1.0f + var * 100.0f);
  }
}

// ---------------- 6. combine: softmax over K, weighted warp ----------------
__launch_bounds__(256)
__global__ void combine_kernel(const float* __restrict__ tkv, const float* __restrict__ geo,
                               const int* __restrict__ tki, const float* __restrict__ posB,
                               float* __restrict__ warp) {
  int id = blockIdx.x * 256 + threadIdx.x;  // b*NN + n
  int b = id / NN;
  const float* vals = tkv + (size_t)id * NK;
  const float* g    = geo + (size_t)id * NK;
  const int*   ix   = tki + (size_t)id * NK;
  const float* pB   = posB + (size_t)b * NN * 2;
  float l[8], mx = -3.0e38f;
  #pragma unroll
  for (int j = 0; j < 8; j++) {
    l[j] = (vals[j] + 1.5f * g[j]) * INV_TEMP;
    mx = fmaxf(mx, l[j]);
  }
  float sw = 0.0f, wx = 0.0f, wy = 0.0f;
  #pragma unroll
  for (int j = 0; j < 8; j++) {
    float w = __expf(l[j] - mx);
    int jj = ix[j];
    sw += w;
    wx = fmaf(w, pB[(size_t)jj * 2], wx);
    wy = fmaf(w, pB[(size_t)jj * 2 + 1], wy);
  }
  warp[(size_t)id * 2]     = wx / sw;
  warp[(size_t)id * 2 + 1] = wy / sw;
}

extern "C" void kernel_launch(void* const* d_in, const int* in_sizes, int n_in,
                              void* d_out, int out_size, void* d_ws, size_t ws_size,
                              hipStream_t stream) {
  const float* fA = (const float*)d_in[0];
  const float* fB = (const float*)d_in[1];
  const float* pA = (const float*)d_in[2];
  const float* pB = (const float*)d_in[3];

  float* out  = (float*)d_out;
  float* warp = out;                       // [B,N,2]
  float* ent  = out + (size_t)NB * NN * 2; // [B,N]
  float* sim  = ent + (size_t)NB * NN;     // [B,N,N] raw_sim (also Sinkhorn cost)

  __hip_bfloat16* Ah = (__hip_bfloat16*)d_ws;
  __hip_bfloat16* Al = Ah + (size_t)NB * NN * NC;
  __hip_bfloat16* Bh = Al + (size_t)NB * NN * NC;
  __hip_bfloat16* Bl = Bh + (size_t)NB * NN * NC;
  float* uu  = (float*)(Bl + (size_t)NB * NN * NC);
  float* vv  = uu + NB * (NN + 1);
  float* tkv = vv + NB * (NN + 1);
  int*   tki = (int*)(tkv + (size_t)NB * NN * NK);
  float* geo = (float*)(tki + (size_t)NB * NN * NK);

  hipMemsetAsync(vv, 0, NB * (NN + 1) * sizeof(float), stream);

  norm_split<<<dim3(2 * NB * NN), 64, 0, stream>>>(fA, fB, Ah, Al, Bh, Bl);
  gemm_mfma<<<dim3(NN / 128, NN / 128, NB), 256, 0, stream>>>(Ah, Al, Bh, Bl, sim);
  for (int it = 0; it < 5; it++) {
    u_pass<<<dim3(NN + 1, NB), 256, 0, stream>>>(sim, vv, uu);
    v_pass<<<dim3(129, NB), 256, 0, stream>>>(sim, uu, vv);
  }
  finalize_rows<<<dim3(NN, NB), 256, 0, stream>>>(sim, uu, vv, tkv, tki, ent);
  geo_kernel<<<dim3(NK, NB), 256, 0, stream>>>(tki, pA, pB, geo);
  combine_kernel<<<dim3((NB * NN) / 256), 256, 0, stream>>>(tkv, geo, tki, pB, warp);
}

// Round 4
// 402.561 us; speedup vs baseline: 1.5925x; 1.2730x over previous
//
#include <hip/hip_runtime.h>
#include <hip/hip_bf16.h>

// AgriMatcher: normalize(+bf16 hi/lo split) -> MFMA cosine-sim GEMM ->
// fused fp32 log-Sinkhorn(5) (u+v in one matrix pass per iteration) ->
// per-row top-8 (u64-key selection, exact round-2 ordering) + entropy ->
// banded 7x7 local variance geometric score -> softmax warp.
// B=2, N=4096=64x64, C=128, K=8, TEMP=0.05, RADIUS=3.

#define NB 2
#define NN 4096
#define NC 128
#define NK 8
#define VST 4104   // padded stride for u/v vectors

constexpr float INV_TEMP   = 20.0f;
constexpr float NORM_CONST = -9.010913347279289f;    // -log(8192)
constexpr float LOG_DUST   = -0.6931471805599453f;   // log(4096)-log(8192)

typedef __attribute__((ext_vector_type(8))) short bf16x8;
typedef __attribute__((ext_vector_type(4))) float f32x4;

// ---------------- 0. init: v0 = 0 ----------------
__global__ void init_kernel(float* __restrict__ v0) {
  int i = blockIdx.x * 256 + threadIdx.x;
  if (i < NB * VST) v0[i] = 0.0f;
}

// ---------------- 1. L2 normalize rows + bf16 hi/lo split ----------------
__global__ void norm_split(const float* __restrict__ fa, const float* __restrict__ fb,
                           __hip_bfloat16* __restrict__ Ah, __hip_bfloat16* __restrict__ Al,
                           __hip_bfloat16* __restrict__ Bh, __hip_bfloat16* __restrict__ Bl) {
  int row = blockIdx.x;
  bool isB = row >= NB * NN;
  int base = isB ? row - NB * NN : row;
  const float* src = (isB ? fb : fa) + (size_t)base * NC;
  __hip_bfloat16* dh = (isB ? Bh : Ah) + (size_t)base * NC;
  __hip_bfloat16* dl = (isB ? Bl : Al) + (size_t)base * NC;
  int t = threadIdx.x;
  float x0 = src[t], x1 = src[t + 64];
  float ss = x0 * x0 + x1 * x1;
  #pragma unroll
  for (int o = 32; o; o >>= 1) ss += __shfl_xor(ss, o);
  float nrm = fmaxf(sqrtf(ss), 1e-12f);
  float y0 = x0 / nrm, y1 = x1 / nrm;
  __hip_bfloat16 h0 = __float2bfloat16(y0);
  __hip_bfloat16 h1 = __float2bfloat16(y1);
  dh[t] = h0;      dl[t] = __float2bfloat16(y0 - __bfloat162float(h0));
  dh[t + 64] = h1; dl[t + 64] = __float2bfloat16(y1 - __bfloat162float(h1));
}

// ---------------- 2. MFMA GEMM: sim = A.B^T via bf16 hi/lo split ----------------
__launch_bounds__(256, 2)
__global__ void gemm_mfma(const __hip_bfloat16* __restrict__ Ah, const __hip_bfloat16* __restrict__ Al,
                          const __hip_bfloat16* __restrict__ Bh, const __hip_bfloat16* __restrict__ Bl,
                          float* __restrict__ sim) {
  __shared__ __hip_bfloat16 sAh[128 * 64], sAl[128 * 64];
  __shared__ __hip_bfloat16 sBh[128 * 64], sBl[128 * 64];
  const int b = blockIdx.z, m0 = blockIdx.y * 128, n0 = blockIdx.x * 128;
  const int t = threadIdx.x;
  const int wid = t >> 6, l = t & 63, q = l >> 4, lm = l & 15;
  const int wm = (wid >> 1) * 64, wn = (wid & 1) * 64;
  f32x4 acc[4][4] = {};
  const __hip_bfloat16* gAh = Ah + ((size_t)b * NN + m0) * NC;
  const __hip_bfloat16* gAl = Al + ((size_t)b * NN + m0) * NC;
  const __hip_bfloat16* gBh = Bh + ((size_t)b * NN + n0) * NC;
  const __hip_bfloat16* gBl = Bl + ((size_t)b * NN + n0) * NC;

  for (int koff = 0; koff < NC; koff += 64) {
    #pragma unroll
    for (int ii = 0; ii < 4; ii++) {
      int id = t + 256 * ii;
      int row = id >> 3, cc = id & 7;
      int gofs = row * NC + koff + cc * 8;
      int lofs = row * 64 + ((cc ^ (row & 7)) << 3);
      *(float4*)&sAh[lofs] = *(const float4*)(gAh + gofs);
      *(float4*)&sAl[lofs] = *(const float4*)(gAl + gofs);
      *(float4*)&sBh[lofs] = *(const float4*)(gBh + gofs);
      *(float4*)&sBl[lofs] = *(const float4*)(gBl + gofs);
    }
    __syncthreads();
    #pragma unroll
    for (int ks = 0; ks < 2; ks++) {
      int cc = ks * 4 + q;
      bf16x8 a_h[4], a_l[4], b_h[4], b_l[4];
      #pragma unroll
      for (int i = 0; i < 4; i++) {
        int r = wm + i * 16 + lm;
        int ro = r * 64 + ((cc ^ (r & 7)) << 3);
        a_h[i] = *(const bf16x8*)&sAh[ro];
        a_l[i] = *(const bf16x8*)&sAl[ro];
        int n = wn + i * 16 + lm;
        int no = n * 64 + ((cc ^ (n & 7)) << 3);
        b_h[i] = *(const bf16x8*)&sBh[no];
        b_l[i] = *(const bf16x8*)&sBl[no];
      }
      #pragma unroll
      for (int i = 0; i < 4; i++) {
        #pragma unroll
        for (int j = 0; j < 4; j++) {
          acc[i][j] = __builtin_amdgcn_mfma_f32_16x16x32_bf16(a_h[i], b_h[j], acc[i][j], 0, 0, 0);
          acc[i][j] = __builtin_amdgcn_mfma_f32_16x16x32_bf16(a_h[i], b_l[j], acc[i][j], 0, 0, 0);
          acc[i][j] = __builtin_amdgcn_mfma_f32_16x16x32_bf16(a_l[i], b_h[j], acc[i][j], 0, 0, 0);
        }
      }
    }
    __syncthreads();
  }
  // C/D layout (m89-verified): col = lane&15, row = (lane>>4)*4 + reg
  float* ob = sim + (size_t)b * NN * NN;
  #pragma unroll
  for (int i = 0; i < 4; i++) {
    #pragma unroll
    for (int j = 0; j < 4; j++) {
      int col = n0 + wn + j * 16 + lm;
      #pragma unroll
      for (int reg = 0; reg < 4; reg++) {
        int r = m0 + wm + i * 16 + q * 4 + reg;
        ob[(size_t)r * NN + col] = acc[i][j][reg];
      }
    }
  }
}

// ---------------- 3a. fused Sinkhorn pass: u for 8 rows + column partials ----------------
// Block = 512 threads, 8 rows x 4096 cols. E[r][c] = exp(20*s + v_c - 30) kept in regs.
// Row sums -> u_r (in-block, 2 barriers); col partials = exp(-v_c) * sum_r E*exp(u_r)
// = sum_r exp(20*s + u_r - 30), written to part[b][blk][col].
__launch_bounds__(512, 4)
__global__ void sink_fused(const float* __restrict__ sim, const float* __restrict__ vin,
                           float* __restrict__ u, float* __restrict__ part) {
  int blk = blockIdx.x, b = blockIdx.y, t = threadIdx.x;
  int r0 = blk * 8, c0 = t * 8;
  const float* vb = vin + b * VST;
  const float* srow0 = sim + ((size_t)b * NN + r0) * NN + c0;

  float4 va0 = *(const float4*)(vb + c0);
  float4 va1 = *(const float4*)(vb + c0 + 4);
  float vm[8] = {va0.x - 30.0f, va0.y - 30.0f, va0.z - 30.0f, va0.w - 30.0f,
                 va1.x - 30.0f, va1.y - 30.0f, va1.z - 30.0f, va1.w - 30.0f};
  float E[8][8];
  float rp[8];
  #pragma unroll
  for (int r = 0; r < 8; r++) {
    const float4* sp = (const float4*)(srow0 + (size_t)r * NN);
    float4 s0 = sp[0], s1 = sp[1];
    E[r][0] = __expf(fmaf(s0.x, INV_TEMP, vm[0]));
    E[r][1] = __expf(fmaf(s0.y, INV_TEMP, vm[1]));
    E[r][2] = __expf(fmaf(s0.z, INV_TEMP, vm[2]));
    E[r][3] = __expf(fmaf(s0.w, INV_TEMP, vm[3]));
    E[r][4] = __expf(fmaf(s1.x, INV_TEMP, vm[4]));
    E[r][5] = __expf(fmaf(s1.y, INV_TEMP, vm[5]));
    E[r][6] = __expf(fmaf(s1.z, INV_TEMP, vm[6]));
    E[r][7] = __expf(fmaf(s1.w, INV_TEMP, vm[7]));
    rp[r] = ((E[r][0] + E[r][1]) + (E[r][2] + E[r][3]))
          + ((E[r][4] + E[r][5]) + (E[r][6] + E[r][7]));
  }
  #pragma unroll
  for (int r = 0; r < 8; r++) {
    #pragma unroll
    for (int o = 1; o < 64; o <<= 1) rp[r] += __shfl_xor(rp[r], o);
  }
  __shared__ float ws[8][8];   // [wave][row]
  __shared__ float eus[8];
  int w = t >> 6;
  if ((t & 63) == 0) {
    #pragma unroll
    for (int r = 0; r < 8; r++) ws[w][r] = rp[r];
  }
  __syncthreads();
  if (t < 8) {
    float S = 0.0f;
    #pragma unroll
    for (int ww = 0; ww < 8; ww++) S += ws[ww][t];
    S += __expf(vb[NN] - 30.0f);               // dustbin column term
    float ur = NORM_CONST - 30.0f - __logf(S);
    u[b * VST + r0 + t] = ur;
    eus[t] = __expf(ur);
  }
  __syncthreads();
  float eu[8];
  #pragma unroll
  for (int r = 0; r < 8; r++) eu[r] = eus[r];
  float outp[8];
  #pragma unroll
  for (int c = 0; c < 8; c++) {
    float acc = E[0][c] * eu[0];
    #pragma unroll
    for (int r = 1; r < 8; r++) acc = fmaf(E[r][c], eu[r], acc);
    outp[c] = acc * __expf(-30.0f - vm[c]);    // * exp(-v_c)
  }
  float* pp = part + ((size_t)b * 512 + blk) * NN + c0;
  *(float4*)pp       = make_float4(outp[0], outp[1], outp[2], outp[3]);
  *(float4*)(pp + 4) = make_float4(outp[4], outp[5], outp[6], outp[7]);
}

// ---------------- 3b. stage2: reduce column partials -> v; dustbins ----------------
// grid (128, NB): block owns 32 cols; also computes u_dust from vin (redundant,
// deterministic, identical across blocks) and block 0 computes v_dust from u.
__launch_bounds__(256)
__global__ void sink_stage2(const float* __restrict__ part, const float* __restrict__ vin,
                            const float* __restrict__ u, float* __restrict__ vout) {
  int b = blockIdx.y, t = threadIdx.x;
  const float* vb = vin + b * VST;
  // u_dust = LOG_DUST - 30 - log( sum_c exp(v_c-30) + exp(v_dust-30) )
  float sv = 0.0f;
  #pragma unroll
  for (int i = 0; i < 16; i++) sv += __expf(vb[t + (i << 8)] - 30.0f);
  #pragma unroll
  for (int o = 1; o < 64; o <<= 1) sv += __shfl_xor(sv, o);
  __shared__ float sa[4];
  if ((t & 63) == 0) sa[t >> 6] = sv;
  __syncthreads();
  float S_v = sa[0] + sa[1] + sa[2] + sa[3] + __expf(vb[NN] - 30.0f);
  float eud = __expf(LOG_DUST - 60.0f - __logf(S_v));  // exp(u_dust - 30)

  int c = t & 31, h = t >> 5;
  int col = blockIdx.x * 32 + c;
  const float* pb = part + (size_t)b * 512 * NN + col;
  float acc = 0.0f;
  #pragma unroll 4
  for (int j = 0; j < 64; j++) acc += pb[(size_t)(h * 64 + j) * NN];
  __shared__ float red[256];
  red[t] = acc;
  __syncthreads();
  if (h == 0) {
    #pragma unroll
    for (int g = 1; g < 8; g++) acc += red[g * 32 + c];
    vout[b * VST + col] = NORM_CONST - 30.0f - __logf(acc + eud);
  }
  if (blockIdx.x == 0) {
    const float* ub = u + b * VST;
    float su = 0.0f;
    #pragma unroll
    for (int i = 0; i < 16; i++) su += __expf(ub[t + (i << 8)] - 30.0f);
    #pragma unroll
    for (int o = 1; o < 64; o <<= 1) su += __shfl_xor(su, o);
    __shared__ float sb[4];
    if ((t & 63) == 0) sb[t >> 6] = su;
    __syncthreads();
    if (t == 0)
      vout[b * VST + NN] = LOG_DUST - 30.0f - __logf(sb[0] + sb[1] + sb[2] + sb[3] + eud);
  }
}

// ---------------- 4. finalize: top-8 via u64 keys (exact ordering), entropy ----------------
// key = (monotone_f32(z) << 32) | ~n : u64 max == (z desc, index asc) — exactly
// round-2's comparator. z recovered bit-exact from the key -> tkv identical.
__launch_bounds__(256)
__global__ void finalize_rows(const float* __restrict__ sim, const float* __restrict__ u,
                              const float* __restrict__ v, float* __restrict__ tkv,
                              int* __restrict__ tki, float* __restrict__ ent) {
  int m = blockIdx.x, b = blockIdx.y, t = threadIdx.x;
  const float4* srow = (const float4*)(sim + ((size_t)b * NN + m) * NN);
  const float4* v4 = (const float4*)(v + b * VST);
  float um = u[b * VST + m];
  unsigned long long key[16];
  float T1 = 0.0f, T2 = 0.0f;
  #pragma unroll
  for (int i = 0; i < 4; i++) {
    int idx = t + (i << 8);
    float4 s = srow[idx], vv = v4[idx];
    unsigned n0 = 4u * (unsigned)idx;
    float z, e;
    unsigned zb, k;
    z = fmaf(s.x, INV_TEMP, vv.x + um); e = __expf(z); T1 += e; T2 = fmaf(e, z, T2);
    zb = __float_as_uint(z); k = (zb & 0x80000000u) ? ~zb : (zb | 0x80000000u);
    key[4 * i + 0] = ((unsigned long long)k << 32) | (unsigned)(~n0);
    z = fmaf(s.y, INV_TEMP, vv.y + um); e = __expf(z); T1 += e; T2 = fmaf(e, z, T2);
    zb = __float_as_uint(z); k = (zb & 0x80000000u) ? ~zb : (zb | 0x80000000u);
    key[4 * i + 1] = ((unsigned long long)k << 32) | (unsigned)(~(n0 + 1));
    z = fmaf(s.z, INV_TEMP, vv.z + um); e = __expf(z); T1 += e; T2 = fmaf(e, z, T2);
    zb = __float_as_uint(z); k = (zb & 0x80000000u) ? ~zb : (zb | 0x80000000u);
    key[4 * i + 2] = ((unsigned long long)k << 32) | (unsigned)(~(n0 + 2));
    z = fmaf(s.w, INV_TEMP, vv.w + um); e = __expf(z); T1 += e; T2 = fmaf(e, z, T2);
    zb = __float_as_uint(z); k = (zb & 0x80000000u) ? ~zb : (zb | 0x80000000u);
    key[4 * i + 3] = ((unsigned long long)k << 32) | (unsigned)(~(n0 + 3));
  }
  #pragma unroll
  for (int o = 1; o < 64; o <<= 1) { T1 += __shfl_xor(T1, o); T2 += __shfl_xor(T2, o); }

  // wave-local top-8 (no barriers)
  unsigned long long wv[8];
  #pragma unroll
  for (int r = 0; r < 8; r++) {
    unsigned long long mx = key[0];
    #pragma unroll
    for (int i = 1; i < 16; i++) mx = (key[i] > mx) ? key[i] : mx;
    #pragma unroll
    for (int o = 1; o < 64; o <<= 1) {
      unsigned long long om = __shfl_xor(mx, o);
      mx = (om > mx) ? om : mx;
    }
    wv[r] = mx;
    #pragma unroll
    for (int i = 0; i < 16; i++) key[i] = (key[i] == mx) ? 0ull : key[i];
  }

  __shared__ unsigned long long lv[4][8];
  __shared__ unsigned long long fv[8];
  __shared__ float sT1[4], sT2[4];
  int wid = t >> 6;
  if ((t & 63) == 0) {
    sT1[wid] = T1; sT2[wid] = T2;
    #pragma unroll
    for (int j = 0; j < 8; j++) lv[wid][j] = wv[j];
  }
  __syncthreads();
  if (t == 0) {
    int p[4] = {0, 0, 0, 0};
    for (int k2 = 0; k2 < 8; k2++) {
      unsigned long long best = 0ull; int bw = 0;
      #pragma unroll
      for (int w = 0; w < 4; w++) {
        if (p[w] < 8 && lv[w][p[w]] > best) { best = lv[w][p[w]]; bw = w; }
      }
      fv[k2] = best; p[bw]++;
    }
  }
  __syncthreads();
  size_t ro = ((size_t)b * NN + m) * NK;
  if (t < 8) {
    unsigned long long kk = fv[t];
    unsigned kh = (unsigned)(kk >> 32);
    unsigned zb = (kh & 0x80000000u) ? (kh & 0x7FFFFFFFu) : ~kh;
    tkv[ro + t] = __expf(__uint_as_float(zb));
    tki[ro + t] = (int)(~(unsigned)kk);
  }
  if (t == 0) {
    float T1t = sT1[0] + sT1[1] + sT1[2] + sT1[3];
    float T2t = sT2[0] + sT2[1] + sT2[2] + sT2[3];
    float denom = T1t + 1e-8f;
    float ld = __logf(denom);
    ent[b * NN + m] = (T1t * ld - T2t) / denom;
  }
}

// ---------------- 5. geometric score: banded 7x7 local variance ----------------
__launch_bounds__(256)
__global__ void geo_kernel(const int* __restrict__ tki, const float* __restrict__ posA,
                           const float* __restrict__ posB, float* __restrict__ geo) {
  int k = blockIdx.x, band = blockIdx.y, b = blockIdx.z, t = threadIdx.x;
  int r0 = band * 8, rlo = r0 - 3;
  __shared__ float s1[14 * 64], s2[14 * 64], h1[14 * 64], h2[14 * 64];
  const float* pA = posA + (size_t)b * NN * 2;
  const float* pB = posB + (size_t)b * NN * 2;
  const int* idx = tki + (size_t)b * NN * NK + k;
  for (int e = t; e < 14 * 64; e += 256) {
    int rr = rlo + (e >> 6), w = e & 63;
    float v1 = 0.0f, v2 = 0.0f;
    if (rr >= 0 && rr < 64) {
      int n = rr * 64 + w;
      int j = idx[(size_t)n * NK];
      float dx = pB[(size_t)j * 2]     - pA[(size_t)n * 2];
      float dy = pB[(size_t)j * 2 + 1] - pA[(size_t)n * 2 + 1];
      v1 = dx + dy;
      v2 = dx * dx + dy * dy;
    }
    s1[e] = v1; s2[e] = v2;
  }
  __syncthreads();
  for (int e = t; e < 14 * 64; e += 256) {
    int w = e & 63, base = e - w;
    float a1 = 0.0f, a2 = 0.0f;
    for (int dw = -3; dw <= 3; dw++) {
      int ww = w + dw;
      if (ww >= 0 && ww < 64) { a1 += s1[base + ww]; a2 += s2[base + ww]; }
    }
    h1[e] = a1; h2[e] = a2;
  }
  __syncthreads();
  for (int o = t; o < 8 * 64; o += 256) {
    int lr = (o >> 6) + 3, w = o & 63;
    int e = lr * 64 + w;
    float b1 = 0.0f, b2 = 0.0f;
    #pragma unroll
    for (int dh = -3; dh <= 3; dh++) { b1 += h1[e + dh * 64]; b2 += h2[e + dh * 64]; }
    float mean = b1 * (1.0f / 98.0f);
    float var = (b2 - b1 * mean) * (1.0f / 97.0f);
    int n = (r0 + (o >> 6)) * 64 + w;
    geo[((size_t)b * NN + n) * NK + k] = 1.0f / (1.0f + var * 100.0f);
  }
}

// ---------------- 6. combine: softmax over K, weighted warp ----------------
__launch_bounds__(256)
__global__ void combine_kernel(const float* __restrict__ tkv, const float* __restrict__ geo,
                               const int* __restrict__ tki, const float* __restrict__ posB,
                               float* __restrict__ warp) {
  int id = blockIdx.x * 256 + threadIdx.x;
  int b = id / NN;
  const float* vals = tkv + (size_t)id * NK;
  const float* g    = geo + (size_t)id * NK;
  const int*   ix   = tki + (size_t)id * NK;
  const float* pB   = posB + (size_t)b * NN * 2;
  float l[8], mx = -3.0e38f;
  #pragma unroll
  for (int j = 0; j < 8; j++) {
    l[j] = (vals[j] + 1.5f * g[j]) * INV_TEMP;
    mx = fmaxf(mx, l[j]);
  }
  float sw = 0.0f, wx = 0.0f, wy = 0.0f;
  #pragma unroll
  for (int j = 0; j < 8; j++) {
    float w = __expf(l[j] - mx);
    int jj = ix[j];
    sw += w;
    wx = fmaf(w, pB[(size_t)jj * 2], wx);
    wy = fmaf(w, pB[(size_t)jj * 2 + 1], wy);
  }
  warp[(size_t)id * 2]     = wx / sw;
  warp[(size_t)id * 2 + 1] = wy / sw;
}

extern "C" void kernel_launch(void* const* d_in, const int* in_sizes, int n_in,
                              void* d_out, int out_size, void* d_ws, size_t ws_size,
                              hipStream_t stream) {
  const float* fA = (const float*)d_in[0];
  const float* fB = (const float*)d_in[1];
  const float* pA = (const float*)d_in[2];
  const float* pB = (const float*)d_in[3];

  float* out  = (float*)d_out;
  float* warp = out;                       // [B,N,2]
  float* ent  = out + (size_t)NB * NN * 2; // [B,N]
  float* sim  = ent + (size_t)NB * NN;     // [B,N,N] raw_sim (also Sinkhorn cost)

  size_t off = 0;
  auto take = [&](size_t bytes) {
    void* p = (char*)d_ws + off;
    off = (off + bytes + 255) & ~(size_t)255;
    return p;
  };
  __hip_bfloat16* Ah = (__hip_bfloat16*)take((size_t)NB * NN * NC * 2);
  __hip_bfloat16* Al = (__hip_bfloat16*)take((size_t)NB * NN * NC * 2);
  __hip_bfloat16* Bh = (__hip_bfloat16*)take((size_t)NB * NN * NC * 2);
  __hip_bfloat16* Bl = (__hip_bfloat16*)take((size_t)NB * NN * NC * 2);
  float* uu   = (float*)take((size_t)NB * VST * 4);
  float* v0   = (float*)take((size_t)NB * VST * 4);
  float* v1   = (float*)take((size_t)NB * VST * 4);
  float* part = (float*)take((size_t)NB * 512 * NN * 4);
  float* tkv  = (float*)take((size_t)NB * NN * NK * 4);
  int*   tki  = (int*)take((size_t)NB * NN * NK * 4);
  float* geo  = (float*)take((size_t)NB * NN * NK * 4);
  (void)off; (void)ws_size;

  init_kernel<<<dim3((NB * VST + 255) / 256), 256, 0, stream>>>(v0);
  norm_split<<<dim3(2 * NB * NN), 64, 0, stream>>>(fA, fB, Ah, Al, Bh, Bl);
  gemm_mfma<<<dim3(NN / 128, NN / 128, NB), 256, 0, stream>>>(Ah, Al, Bh, Bl, sim);
  for (int it = 0; it < 5; it++) {
    float* vin  = (it & 1) ? v1 : v0;
    float* vout = (it & 1) ? v0 : v1;
    sink_fused<<<dim3(NN / 8, NB), 512, 0, stream>>>(sim, vin, uu, part);
    sink_stage2<<<dim3(128, NB), 256, 0, stream>>>(part, vin, uu, vout);
  }
  finalize_rows<<<dim3(NN, NB), 256, 0, stream>>>(sim, uu, v1, tkv, tki, ent);
  geo_kernel<<<dim3(NK, 8, NB), 256, 0, stream>>>(tki, pA, pB, geo);
  combine_kernel<<<dim3((NB * NN) / 256), 256, 0, stream>>>(tkv, geo, tki, pB, warp);
}